// Round 1
// baseline (74.809 us; speedup 1.0000x reference)
//
#include <hip/hip_runtime.h>
#include <hip/hip_bf16.h>
#include <stdint.h>

#define N_CELLS 196608
#define NH 9
#define F 64            // F_IN == F_OUT == 64
#define K_TOT (NH * F)  // 576
#define K_STEPS (K_TOT / 32)  // 18

typedef __attribute__((ext_vector_type(8))) short bf16x8;
typedef __attribute__((ext_vector_type(4))) float f32x4;

__device__ inline unsigned short f2bf(float f) {
    union { float f; uint32_t u; } v; v.f = f;
    uint32_t u = v.u;
    // round-to-nearest-even
    uint32_t r = u + 0x7FFFu + ((u >> 16) & 1u);
    return (unsigned short)(r >> 16);
}

// ---------------- x: fp32 -> bf16, flat, vectorized -----------------------
__global__ __launch_bounds__(256) void convert_x_kernel(
        const float* __restrict__ x, unsigned short* __restrict__ xb) {
    size_t i = (size_t)blockIdx.x * blockDim.x + threadIdx.x;  // one per 8 elems
    const f32x4* p = reinterpret_cast<const f32x4*>(x);
    f32x4 a = p[i * 2], b = p[i * 2 + 1];
    unsigned short tmp[8];
    #pragma unroll
    for (int j = 0; j < 4; ++j) { tmp[j] = f2bf(a[j]); tmp[4 + j] = f2bf(b[j]); }
    *reinterpret_cast<bf16x8*>(xb + i * 8) = *reinterpret_cast<const bf16x8*>(tmp);
}

// ---------------- W: fp32 [576][64] -> bf16 MFMA B-fragment layout --------
// frag id = kk*4 + t  (kk = K-step 0..17, t = 16-col tile 0..3)
// lane l holds 8 bf16: B[k = kk*32 + (l>>4)*8 + j][o = t*16 + (l&15)]
// stored contiguously at wb[(frag*64 + l)*8 + j]
__global__ __launch_bounds__(256) void convert_w_kernel(
        const float* __restrict__ W, unsigned short* __restrict__ wb) {
    int tid = blockIdx.x * blockDim.x + threadIdx.x;  // 0 .. 4607
    int l = tid & 63;
    int frag = tid >> 6;          // 0..71
    int kk = frag >> 2, t = frag & 3;
    int k0 = kk * 32 + (l >> 4) * 8;
    int o  = t * 16 + (l & 15);
    unsigned short tmp[8];
    #pragma unroll
    for (int j = 0; j < 8; ++j) tmp[j] = f2bf(W[(size_t)(k0 + j) * F + o]);
    *reinterpret_cast<bf16x8*>(wb + (size_t)tid * 8) =
        *reinterpret_cast<const bf16x8*>(tmp);
}

// ---------------- fused gather + GEMM -------------------------------------
// Block: 64 cells, 256 threads = 4 waves. Wave w owns cells [w*16, w*16+16),
// computes 16x64 outputs = 4 MFMA tiles, K-loop over 9 neighbors x 2 steps.
// A-frag (16x32): lane l holds x_bf16[adjc[cell][j]][h*32 + (l>>4)*8 .. +8)
// for cell = base + (l&15). B-frags come pre-swizzled from wb.
template <bool XB>
__global__ __launch_bounds__(256) void fused_gather_gemm(
        const float* __restrict__ x32, const unsigned short* __restrict__ xb,
        const int* __restrict__ adjc, const unsigned short* __restrict__ wb,
        float* __restrict__ out) {
    const int wave = threadIdx.x >> 6;
    const int lane = threadIdx.x & 63;
    const int lo = lane & 15, hi = lane >> 4;
    const int cellbase = blockIdx.x * 64 + wave * 16;
    const int cell = cellbase + lo;   // A-operand row for this lane

    f32x4 acc[4] = {f32x4{0,0,0,0}, f32x4{0,0,0,0}, f32x4{0,0,0,0}, f32x4{0,0,0,0}};
    const size_t adj_base = (size_t)cell * NH;

    #pragma unroll
    for (int j = 0; j < NH; ++j) {
        const int idx = adjc[adj_base + j];
        #pragma unroll
        for (int h = 0; h < 2; ++h) {
            bf16x8 a;
            if (XB) {
                a = *reinterpret_cast<const bf16x8*>(
                        xb + (size_t)idx * F + h * 32 + hi * 8);
            } else {
                const float* ap = x32 + (size_t)idx * F + h * 32 + hi * 8;
                f32x4 f0 = *reinterpret_cast<const f32x4*>(ap);
                f32x4 f1 = *reinterpret_cast<const f32x4*>(ap + 4);
                unsigned short tmp[8];
                #pragma unroll
                for (int q = 0; q < 4; ++q) { tmp[q] = f2bf(f0[q]); tmp[4+q] = f2bf(f1[q]); }
                a = *reinterpret_cast<const bf16x8*>(tmp);
            }
            const int kk = j * 2 + h;
            #pragma unroll
            for (int t = 0; t < 4; ++t) {
                bf16x8 b = *reinterpret_cast<const bf16x8*>(
                        wb + ((size_t)(kk * 4 + t) * 64 + lane) * 8);
                acc[t] = __builtin_amdgcn_mfma_f32_16x16x32_bf16(a, b, acc[t], 0, 0, 0);
            }
        }
    }

    // C/D layout: col = lane&15, row = (lane>>4)*4 + r   [measured m89/m91]
    #pragma unroll
    for (int t = 0; t < 4; ++t) {
        #pragma unroll
        for (int r = 0; r < 4; ++r) {
            int row = cellbase + hi * 4 + r;
            out[(size_t)row * F + t * 16 + lo] = acc[t][r];
        }
    }
}

// ---------------- correctness-only fallback (no workspace) ----------------
__global__ void naive_kernel(const float* __restrict__ x,
                             const int* __restrict__ adjc,
                             const float* __restrict__ W,
                             float* __restrict__ out) {
    int n = blockIdx.x;
    int o = threadIdx.x;  // 64 threads
    float acc = 0.f;
    for (int j = 0; j < NH; ++j) {
        int idx = adjc[(size_t)n * NH + j];
        for (int f = 0; f < F; ++f)
            acc += x[(size_t)idx * F + f] * W[(size_t)(j * F + f) * F + o];
    }
    out[(size_t)n * F + o] = acc;
}

extern "C" void kernel_launch(void* const* d_in, const int* in_sizes, int n_in,
                              void* d_out, int out_size, void* d_ws, size_t ws_size,
                              hipStream_t stream) {
    const float* x    = (const float*)d_in[0];
    const int*   adjc = (const int*)d_in[1];
    const float* W    = (const float*)d_in[2];
    float* out = (float*)d_out;

    const size_t need_x = (size_t)N_CELLS * F * sizeof(unsigned short);  // 25165824
    const size_t need_w = (size_t)K_TOT * F * sizeof(unsigned short);    // 73728

    if (ws_size >= need_x + need_w) {
        unsigned short* xb = (unsigned short*)d_ws;
        unsigned short* wb = (unsigned short*)((char*)d_ws + need_x);
        convert_x_kernel<<<(N_CELLS * F / 8) / 256, 256, 0, stream>>>(x, xb);
        convert_w_kernel<<<(K_STEPS * 4 * 64) / 256, 256, 0, stream>>>(W, wb);
        fused_gather_gemm<true><<<N_CELLS / 64, 256, 0, stream>>>(x, xb, adjc, wb, out);
    } else if (ws_size >= need_w) {
        unsigned short* wb = (unsigned short*)d_ws;
        convert_w_kernel<<<(K_STEPS * 4 * 64) / 256, 256, 0, stream>>>(W, wb);
        fused_gather_gemm<false><<<N_CELLS / 64, 256, 0, stream>>>(x, nullptr, adjc, wb, out);
    } else {
        naive_kernel<<<N_CELLS, F, 0, stream>>>(x, adjc, W, out);
    }
}

// Round 2
// 71.335 us; speedup vs baseline: 1.0487x; 1.0487x over previous
//
#include <hip/hip_runtime.h>
#include <hip/hip_bf16.h>
#include <stdint.h>

#define N_CELLS 196608
#define NH 9
#define F 64            // F_IN == F_OUT == 64
#define K_TOT (NH * F)  // 576
#define K_STEPS (K_TOT / 32)  // 18

typedef __attribute__((ext_vector_type(8))) short bf16x8;
typedef __attribute__((ext_vector_type(4))) float f32x4;

__device__ inline unsigned short f2bf(float f) {
    union { float f; uint32_t u; } v; v.f = f;
    uint32_t u = v.u;
    uint32_t r = u + 0x7FFFu + ((u >> 16) & 1u);  // round-to-nearest-even
    return (unsigned short)(r >> 16);
}

// ---------------- x: fp32 -> bf16, flat, vectorized -----------------------
__global__ __launch_bounds__(256) void convert_x_kernel(
        const float* __restrict__ x, unsigned short* __restrict__ xb) {
    size_t i = (size_t)blockIdx.x * blockDim.x + threadIdx.x;  // one per 8 elems
    const f32x4* p = reinterpret_cast<const f32x4*>(x);
    f32x4 a = p[i * 2], b = p[i * 2 + 1];
    unsigned short tmp[8];
    #pragma unroll
    for (int j = 0; j < 4; ++j) { tmp[j] = f2bf(a[j]); tmp[4 + j] = f2bf(b[j]); }
    *reinterpret_cast<bf16x8*>(xb + i * 8) = *reinterpret_cast<const bf16x8*>(tmp);
}

// ---------------- W: fp32 [576][64] -> bf16 MFMA B-fragment layout --------
// frag id = kk*4 + t  (kk = K-step 0..17, t = 16-col tile 0..3)
// lane l holds 8 bf16: B[k = kk*32 + (l>>4)*8 + j][o = t*16 + (l&15)]
__global__ __launch_bounds__(256) void convert_w_kernel(
        const float* __restrict__ W, unsigned short* __restrict__ wb) {
    int tid = blockIdx.x * blockDim.x + threadIdx.x;  // 0 .. 4607
    int l = tid & 63;
    int frag = tid >> 6;          // 0..71
    int kk = frag >> 2, t = frag & 3;
    int k0 = kk * 32 + (l >> 4) * 8;
    int o  = t * 16 + (l & 15);
    unsigned short tmp[8];
    #pragma unroll
    for (int j = 0; j < 8; ++j) tmp[j] = f2bf(W[(size_t)(k0 + j) * F + o]);
    *reinterpret_cast<bf16x8*>(wb + (size_t)tid * 8) =
        *reinterpret_cast<const bf16x8*>(tmp);
}

// ---------------- fused gather + GEMM, v2: 64 cells per wave --------------
// Block: 256 cells, 4 waves; wave owns 64 cells = 4 MFMA A-tiles (m=0..3).
// Per K-step kk: 4 B-frag loads (t=0..3) reused across the 4 A-tiles
// -> 16 MFMAs per step, B L2-traffic cut 4x vs v1.
// A for neighbor j+1 prefetched before j's MFMAs (8 independent gathers
// in flight); all adjc indices loaded up front.
template <bool XB>
__global__ __launch_bounds__(256) void fused_gather_gemm_v2(
        const float* __restrict__ x32, const unsigned short* __restrict__ xb,
        const int* __restrict__ adjc, const unsigned short* __restrict__ wb,
        float* __restrict__ out) {
    const int wave = threadIdx.x >> 6;
    const int lane = threadIdx.x & 63;
    const int lo = lane & 15, hi = lane >> 4;
    const int cellbase = blockIdx.x * 256 + wave * 64;

    // All neighbor indices up front (lane's A-row cell depends on lo only).
    int idx[4][NH];
    #pragma unroll
    for (int m = 0; m < 4; ++m) {
        const int* ap = adjc + (size_t)(cellbase + m * 16 + lo) * NH;
        #pragma unroll
        for (int j = 0; j < NH; ++j) idx[m][j] = ap[j];
    }

    f32x4 acc[4][4];
    #pragma unroll
    for (int m = 0; m < 4; ++m)
        #pragma unroll
        for (int t = 0; t < 4; ++t) acc[m][t] = f32x4{0.f, 0.f, 0.f, 0.f};

    auto loadA = [&](int m, int j, int h) -> bf16x8 {
        if (XB) {
            return *reinterpret_cast<const bf16x8*>(
                    xb + (size_t)idx[m][j] * F + h * 32 + hi * 8);
        } else {
            const float* ap = x32 + (size_t)idx[m][j] * F + h * 32 + hi * 8;
            f32x4 f0 = *reinterpret_cast<const f32x4*>(ap);
            f32x4 f1 = *reinterpret_cast<const f32x4*>(ap + 4);
            unsigned short tmp[8];
            #pragma unroll
            for (int q = 0; q < 4; ++q) { tmp[q] = f2bf(f0[q]); tmp[4+q] = f2bf(f1[q]); }
            return *reinterpret_cast<const bf16x8*>(tmp);
        }
    };

    bf16x8 aC[4][2];
    #pragma unroll
    for (int m = 0; m < 4; ++m)
        #pragma unroll
        for (int h = 0; h < 2; ++h) aC[m][h] = loadA(m, 0, h);

    #pragma unroll
    for (int j = 0; j < NH; ++j) {
        // Prefetch neighbor j+1 before consuming j (folds under full unroll).
        bf16x8 aN[4][2];
        if (j + 1 < NH) {
            #pragma unroll
            for (int m = 0; m < 4; ++m)
                #pragma unroll
                for (int h = 0; h < 2; ++h) aN[m][h] = loadA(m, j + 1, h);
        }
        #pragma unroll
        for (int h = 0; h < 2; ++h) {
            const int kk = j * 2 + h;
            #pragma unroll
            for (int t = 0; t < 4; ++t) {
                bf16x8 b = *reinterpret_cast<const bf16x8*>(
                        wb + ((size_t)(kk * 4 + t) * 64 + lane) * 8);
                #pragma unroll
                for (int m = 0; m < 4; ++m)
                    acc[m][t] = __builtin_amdgcn_mfma_f32_16x16x32_bf16(
                            aC[m][h], b, acc[m][t], 0, 0, 0);
            }
        }
        if (j + 1 < NH) {
            #pragma unroll
            for (int m = 0; m < 4; ++m)
                #pragma unroll
                for (int h = 0; h < 2; ++h) aC[m][h] = aN[m][h];
        }
    }

    // C/D layout: col = lane&15, row = (lane>>4)*4 + r   [measured m89/m91]
    #pragma unroll
    for (int m = 0; m < 4; ++m)
        #pragma unroll
        for (int t = 0; t < 4; ++t)
            #pragma unroll
            for (int r = 0; r < 4; ++r) {
                int row = cellbase + m * 16 + hi * 4 + r;
                out[(size_t)row * F + t * 16 + lo] = acc[m][t][r];
            }
}

// ---------------- correctness-only fallback (no workspace) ----------------
__global__ void naive_kernel(const float* __restrict__ x,
                             const int* __restrict__ adjc,
                             const float* __restrict__ W,
                             float* __restrict__ out) {
    int n = blockIdx.x;
    int o = threadIdx.x;  // 64 threads
    float acc = 0.f;
    for (int j = 0; j < NH; ++j) {
        int idx = adjc[(size_t)n * NH + j];
        for (int f = 0; f < F; ++f)
            acc += x[(size_t)idx * F + f] * W[(size_t)(j * F + f) * F + o];
    }
    out[(size_t)n * F + o] = acc;
}

extern "C" void kernel_launch(void* const* d_in, const int* in_sizes, int n_in,
                              void* d_out, int out_size, void* d_ws, size_t ws_size,
                              hipStream_t stream) {
    const float* x    = (const float*)d_in[0];
    const int*   adjc = (const int*)d_in[1];
    const float* W    = (const float*)d_in[2];
    float* out = (float*)d_out;

    const size_t need_x = (size_t)N_CELLS * F * sizeof(unsigned short);  // 25165824
    const size_t need_w = (size_t)K_TOT * F * sizeof(unsigned short);    // 73728

    if (ws_size >= need_x + need_w) {
        unsigned short* xb = (unsigned short*)d_ws;
        unsigned short* wb = (unsigned short*)((char*)d_ws + need_x);
        convert_x_kernel<<<(N_CELLS * F / 8) / 256, 256, 0, stream>>>(x, xb);
        convert_w_kernel<<<(K_STEPS * 4 * 64) / 256, 256, 0, stream>>>(W, wb);
        fused_gather_gemm_v2<true><<<N_CELLS / 256, 256, 0, stream>>>(
                x, xb, adjc, wb, out);
    } else if (ws_size >= need_w) {
        unsigned short* wb = (unsigned short*)d_ws;
        convert_w_kernel<<<(K_STEPS * 4 * 64) / 256, 256, 0, stream>>>(W, wb);
        fused_gather_gemm_v2<false><<<N_CELLS / 256, 256, 0, stream>>>(
                x, nullptr, adjc, wb, out);
    } else {
        naive_kernel<<<N_CELLS, F, 0, stream>>>(x, adjc, W, out);
    }
}

// Round 3
// 61.885 us; speedup vs baseline: 1.2088x; 1.1527x over previous
//
#include <hip/hip_runtime.h>
#include <hip/hip_bf16.h>
#include <stdint.h>

#define N_CELLS 196608
#define NH 9
#define F 64            // F_IN == F_OUT == 64
#define K_TOT (NH * F)  // 576
#define K_STEPS (K_TOT / 32)  // 18
#define NFRAG (K_STEPS * 4)   // 72 B-fragments
#define WLDS_SHORTS (NFRAG * 64 * 8)  // 36864 shorts = 72 KB

typedef __attribute__((ext_vector_type(8))) short bf16x8;
typedef __attribute__((ext_vector_type(4))) float f32x4;

__device__ inline unsigned short f2bf(float f) {
    union { float f; uint32_t u; } v; v.f = f;
    uint32_t u = v.u;
    uint32_t r = u + 0x7FFFu + ((u >> 16) & 1u);  // round-to-nearest-even
    return (unsigned short)(r >> 16);
}

// ---------------- x: fp32 -> bf16, flat, vectorized -----------------------
__global__ __launch_bounds__(256) void convert_x_kernel(
        const float* __restrict__ x, unsigned short* __restrict__ xb) {
    size_t i = (size_t)blockIdx.x * blockDim.x + threadIdx.x;  // one per 8 elems
    const f32x4* p = reinterpret_cast<const f32x4*>(x);
    f32x4 a = p[i * 2], b = p[i * 2 + 1];
    unsigned short tmp[8];
    #pragma unroll
    for (int j = 0; j < 4; ++j) { tmp[j] = f2bf(a[j]); tmp[4 + j] = f2bf(b[j]); }
    *reinterpret_cast<bf16x8*>(xb + i * 8) = *reinterpret_cast<const bf16x8*>(tmp);
}

// ---------------- W: fp32 [576][64] -> bf16 MFMA B-fragment layout --------
// frag id = kk*4 + t  (kk = K-step 0..17, t = 16-col tile 0..3)
// lane l holds 8 bf16: B[k = kk*32 + (l>>4)*8 + j][o = t*16 + (l&15)]
__global__ __launch_bounds__(256) void convert_w_kernel(
        const float* __restrict__ W, unsigned short* __restrict__ wb) {
    int tid = blockIdx.x * blockDim.x + threadIdx.x;  // 0 .. 4607
    int l = tid & 63;
    int frag = tid >> 6;          // 0..71
    int kk = frag >> 2, t = frag & 3;
    int k0 = kk * 32 + (l >> 4) * 8;
    int o  = t * 16 + (l & 15);
    unsigned short tmp[8];
    #pragma unroll
    for (int j = 0; j < 8; ++j) tmp[j] = f2bf(W[(size_t)(k0 + j) * F + o]);
    *reinterpret_cast<bf16x8*>(wb + (size_t)tid * 8) =
        *reinterpret_cast<const bf16x8*>(tmp);
}

// ---------------- fused gather + GEMM, v3: W in LDS ------------------------
// Key change vs v2: B-fragments come from LDS (lgkmcnt), so the vmcnt counter
// carries ONLY the A-gather loads -> the j+1 prefetch genuinely overlaps the
// MFMAs of iteration j (previously every B-load consumption drained the
// prefetched gathers, serializing full gather latency per j).
// Block: 256 threads = 4 waves, 256 cells; wave owns 64 cells (4 A-tiles).
// LDS: 72 KB W copy -> 2 blocks/CU.
template <bool XB>
__global__ __launch_bounds__(256, 2) void fused_gather_gemm_v3(
        const float* __restrict__ x32, const unsigned short* __restrict__ xb,
        const int* __restrict__ adjc, const unsigned short* __restrict__ wb,
        float* __restrict__ out) {
    __shared__ unsigned short wlds[WLDS_SHORTS];

    const int wave = threadIdx.x >> 6;
    const int lane = threadIdx.x & 63;
    const int lo = lane & 15, hi = lane >> 4;
    const int cellbase = blockIdx.x * 256 + wave * 64;

    // --- neighbor indices: j=0 first (unblocks the first gather), rest after
    int idx[4][NH];
    #pragma unroll
    for (int m = 0; m < 4; ++m)
        idx[m][0] = __builtin_nontemporal_load(
                adjc + (size_t)(cellbase + m * 16 + lo) * NH);

    auto loadA = [&](int m, int j, int h) -> bf16x8 {
        if (XB) {
            return *reinterpret_cast<const bf16x8*>(
                    xb + (size_t)idx[m][j] * F + h * 32 + hi * 8);
        } else {
            const float* ap = x32 + (size_t)idx[m][j] * F + h * 32 + hi * 8;
            f32x4 f0 = *reinterpret_cast<const f32x4*>(ap);
            f32x4 f1 = *reinterpret_cast<const f32x4*>(ap + 4);
            unsigned short tmp[8];
            #pragma unroll
            for (int q = 0; q < 4; ++q) { tmp[q] = f2bf(f0[q]); tmp[4+q] = f2bf(f1[q]); }
            return *reinterpret_cast<const bf16x8*>(tmp);
        }
    };

    // --- issue gather j=0 as early as possible
    bf16x8 aC[4][2];
    #pragma unroll
    for (int m = 0; m < 4; ++m)
        #pragma unroll
        for (int h = 0; h < 2; ++h) aC[m][h] = loadA(m, 0, h);

    // --- remaining adjc (latency hidden under W staging)
    #pragma unroll
    for (int m = 0; m < 4; ++m) {
        const int* ap = adjc + (size_t)(cellbase + m * 16 + lo) * NH;
        #pragma unroll
        for (int j = 1; j < NH; ++j) idx[m][j] = __builtin_nontemporal_load(ap + j);
    }

    // --- stage W into LDS (4608 bf16x8 vectors; 18 per thread, coalesced)
    {
        const bf16x8* src = reinterpret_cast<const bf16x8*>(wb);
        bf16x8* dst = reinterpret_cast<bf16x8*>(wlds);
        #pragma unroll
        for (int it = 0; it < 18; ++it)
            dst[it * 256 + threadIdx.x] = src[it * 256 + threadIdx.x];
    }
    __syncthreads();

    f32x4 acc[4][4];
    #pragma unroll
    for (int m = 0; m < 4; ++m)
        #pragma unroll
        for (int t = 0; t < 4; ++t) acc[m][t] = f32x4{0.f, 0.f, 0.f, 0.f};

    #pragma unroll
    for (int j = 0; j < NH; ++j) {
        // Prefetch neighbor j+1 (vmcnt holds ONLY these 8 loads now).
        bf16x8 aN[4][2];
        if (j + 1 < NH) {
            #pragma unroll
            for (int m = 0; m < 4; ++m)
                #pragma unroll
                for (int h = 0; h < 2; ++h) aN[m][h] = loadA(m, j + 1, h);
        }
        #pragma unroll
        for (int h = 0; h < 2; ++h) {
            const int kk = j * 2 + h;
            #pragma unroll
            for (int t = 0; t < 4; ++t) {
                // B from LDS: lane-contiguous 16B -> 2-way bank alias (free)
                bf16x8 b = *reinterpret_cast<const bf16x8*>(
                        &wlds[((size_t)(kk * 4 + t) * 64 + lane) * 8]);
                #pragma unroll
                for (int m = 0; m < 4; ++m)
                    acc[m][t] = __builtin_amdgcn_mfma_f32_16x16x32_bf16(
                            aC[m][h], b, acc[m][t], 0, 0, 0);
            }
        }
        if (j + 1 < NH) {
            #pragma unroll
            for (int m = 0; m < 4; ++m)
                #pragma unroll
                for (int h = 0; h < 2; ++h) aC[m][h] = aN[m][h];
        }
    }

    // C/D layout: col = lane&15, row = (lane>>4)*4 + r   [measured m89/m91]
    // nt stores: out is write-once, keep it out of L2 (protect gathered xb).
    #pragma unroll
    for (int m = 0; m < 4; ++m)
        #pragma unroll
        for (int t = 0; t < 4; ++t)
            #pragma unroll
            for (int r = 0; r < 4; ++r) {
                int row = cellbase + m * 16 + hi * 4 + r;
                __builtin_nontemporal_store(
                        acc[m][t][r], &out[(size_t)row * F + t * 16 + lo]);
            }
}

// ---------------- correctness-only fallback (no workspace) ----------------
__global__ void naive_kernel(const float* __restrict__ x,
                             const int* __restrict__ adjc,
                             const float* __restrict__ W,
                             float* __restrict__ out) {
    int n = blockIdx.x;
    int o = threadIdx.x;  // 64 threads
    float acc = 0.f;
    for (int j = 0; j < NH; ++j) {
        int idx = adjc[(size_t)n * NH + j];
        for (int f = 0; f < F; ++f)
            acc += x[(size_t)idx * F + f] * W[(size_t)(j * F + f) * F + o];
    }
    out[(size_t)n * F + o] = acc;
}

extern "C" void kernel_launch(void* const* d_in, const int* in_sizes, int n_in,
                              void* d_out, int out_size, void* d_ws, size_t ws_size,
                              hipStream_t stream) {
    const float* x    = (const float*)d_in[0];
    const int*   adjc = (const int*)d_in[1];
    const float* W    = (const float*)d_in[2];
    float* out = (float*)d_out;

    const size_t need_x = (size_t)N_CELLS * F * sizeof(unsigned short);  // 25165824
    const size_t need_w = (size_t)K_TOT * F * sizeof(unsigned short);    // 73728

    if (ws_size >= need_x + need_w) {
        unsigned short* xb = (unsigned short*)d_ws;
        unsigned short* wb = (unsigned short*)((char*)d_ws + need_x);
        convert_x_kernel<<<(N_CELLS * F / 8) / 256, 256, 0, stream>>>(x, xb);
        convert_w_kernel<<<(K_STEPS * 4 * 64) / 256, 256, 0, stream>>>(W, wb);
        fused_gather_gemm_v3<true><<<N_CELLS / 256, 256, 0, stream>>>(
                x, xb, adjc, wb, out);
    } else if (ws_size >= need_w) {
        unsigned short* wb = (unsigned short*)d_ws;
        convert_w_kernel<<<(K_STEPS * 4 * 64) / 256, 256, 0, stream>>>(W, wb);
        fused_gather_gemm_v3<false><<<N_CELLS / 256, 256, 0, stream>>>(
                x, nullptr, adjc, wb, out);
    } else {
        naive_kernel<<<N_CELLS, F, 0, stream>>>(x, adjc, W, out);
    }
}

// Round 4
// 61.660 us; speedup vs baseline: 1.2132x; 1.0037x over previous
//
#include <hip/hip_runtime.h>
#include <hip/hip_bf16.h>
#include <stdint.h>

#define N_CELLS 196608
#define NH 9
#define F 64            // F_IN == F_OUT == 64
#define K_TOT (NH * F)  // 576
#define K_STEPS (K_TOT / 32)  // 18
#define NFRAG (K_STEPS * 4)   // 72 B-fragments
#define WLDS_SHORTS (NFRAG * 64 * 8)  // 36864 shorts = 72 KB

typedef __attribute__((ext_vector_type(8))) short bf16x8;
typedef __attribute__((ext_vector_type(4))) float f32x4;

__device__ inline unsigned short f2bf(float f) {
    union { float f; uint32_t u; } v; v.f = f;
    uint32_t u = v.u;
    uint32_t r = u + 0x7FFFu + ((u >> 16) & 1u);  // round-to-nearest-even
    return (unsigned short)(r >> 16);
}

// ---------------- x: fp32 -> bf16, flat, vectorized -----------------------
__global__ __launch_bounds__(256) void convert_x_kernel(
        const float* __restrict__ x, unsigned short* __restrict__ xb) {
    size_t i = (size_t)blockIdx.x * blockDim.x + threadIdx.x;  // one per 8 elems
    const f32x4* p = reinterpret_cast<const f32x4*>(x);
    f32x4 a = p[i * 2], b = p[i * 2 + 1];
    unsigned short tmp[8];
    #pragma unroll
    for (int j = 0; j < 4; ++j) { tmp[j] = f2bf(a[j]); tmp[4 + j] = f2bf(b[j]); }
    *reinterpret_cast<bf16x8*>(xb + i * 8) = *reinterpret_cast<const bf16x8*>(tmp);
}

// ---------------- W: fp32 [576][64] -> bf16 MFMA B-fragment layout --------
// frag id = kk*4 + t  (kk = K-step 0..17, t = 16-col tile 0..3)
// lane l holds 8 bf16: B[k = kk*32 + (l>>4)*8 + j][o = t*16 + (l&15)]
__global__ __launch_bounds__(256) void convert_w_kernel(
        const float* __restrict__ W, unsigned short* __restrict__ wb) {
    int tid = blockIdx.x * blockDim.x + threadIdx.x;  // 0 .. 4607
    int l = tid & 63;
    int frag = tid >> 6;          // 0..71
    int kk = frag >> 2, t = frag & 3;
    int k0 = kk * 32 + (l >> 4) * 8;
    int o  = t * 16 + (l & 15);
    unsigned short tmp[8];
    #pragma unroll
    for (int j = 0; j < 8; ++j) tmp[j] = f2bf(W[(size_t)(k0 + j) * F + o]);
    *reinterpret_cast<bf16x8*>(wb + (size_t)tid * 8) =
        *reinterpret_cast<const bf16x8*>(tmp);
}

// ---------------- fused gather + GEMM, v4: depth-2 gather pipeline ---------
// vs v3: A-gathers pipelined 2 j-steps deep in a static ring aS[3] (j-loop
// fully unrolled -> all indices compile-time, no scratch). MFMAs of step j
// wait only on loads issued at step j-2 (compiler emits counted vmcnt(16)),
// keeping ~2x the gather misses in flight at ~100% duty cycle.
// W stays in LDS so B-reads ride lgkmcnt, never draining the gather queue.
template <bool XB>
__global__ __launch_bounds__(256, 2) void fused_gather_gemm_v4(
        const float* __restrict__ x32, const unsigned short* __restrict__ xb,
        const int* __restrict__ adjc, const unsigned short* __restrict__ wb,
        float* __restrict__ out) {
    __shared__ unsigned short wlds[WLDS_SHORTS];

    const int wave = threadIdx.x >> 6;
    const int lane = threadIdx.x & 63;
    const int lo = lane & 15, hi = lane >> 4;
    const int cellbase = blockIdx.x * 256 + wave * 64;

    // --- all neighbor indices up front (latency paid once in prologue)
    int idx[4][NH];
    #pragma unroll
    for (int m = 0; m < 4; ++m) {
        const int* ap = adjc + (size_t)(cellbase + m * 16 + lo) * NH;
        #pragma unroll
        for (int j = 0; j < NH; ++j) idx[m][j] = __builtin_nontemporal_load(ap + j);
    }

    auto loadA = [&](int m, int j, int h) -> bf16x8 {
        if (XB) {
            return *reinterpret_cast<const bf16x8*>(
                    xb + (size_t)idx[m][j] * F + h * 32 + hi * 8);
        } else {
            const float* ap = x32 + (size_t)idx[m][j] * F + h * 32 + hi * 8;
            f32x4 f0 = *reinterpret_cast<const f32x4*>(ap);
            f32x4 f1 = *reinterpret_cast<const f32x4*>(ap + 4);
            unsigned short tmp[8];
            #pragma unroll
            for (int q = 0; q < 4; ++q) { tmp[q] = f2bf(f0[q]); tmp[4+q] = f2bf(f1[q]); }
            return *reinterpret_cast<const bf16x8*>(tmp);
        }
    };

    // --- depth-2 ring of A-slices; issue j=0 and j=1 before W staging
    bf16x8 aS[3][4][2];
    #pragma unroll
    for (int m = 0; m < 4; ++m)
        #pragma unroll
        for (int h = 0; h < 2; ++h) {
            aS[0][m][h] = loadA(m, 0, h);
            aS[1][m][h] = loadA(m, 1, h);
        }

    // --- stage W into LDS (4608 bf16x8 vectors; 18 per thread, coalesced)
    {
        const bf16x8* src = reinterpret_cast<const bf16x8*>(wb);
        bf16x8* dst = reinterpret_cast<bf16x8*>(wlds);
        #pragma unroll
        for (int it = 0; it < 18; ++it)
            dst[it * 256 + threadIdx.x] = src[it * 256 + threadIdx.x];
    }
    __syncthreads();

    f32x4 acc[4][4];
    #pragma unroll
    for (int m = 0; m < 4; ++m)
        #pragma unroll
        for (int t = 0; t < 4; ++t) acc[m][t] = f32x4{0.f, 0.f, 0.f, 0.f};

    #pragma unroll
    for (int j = 0; j < NH; ++j) {
        const int cur = j % 3;            // compile-time after full unroll
        const int nxt = (j + 2) % 3;
        // Prefetch slice j+2 BEFORE consuming slice j: 16 loads stay in
        // flight across this step's MFMAs (compiler waits vmcnt(16)).
        if (j + 2 < NH) {
            #pragma unroll
            for (int m = 0; m < 4; ++m)
                #pragma unroll
                for (int h = 0; h < 2; ++h) aS[nxt][m][h] = loadA(m, j + 2, h);
        }
        #pragma unroll
        for (int h = 0; h < 2; ++h) {
            const int kk = j * 2 + h;
            #pragma unroll
            for (int t = 0; t < 4; ++t) {
                // B from LDS: lane-contiguous 16B -> 2-way bank alias (free)
                bf16x8 b = *reinterpret_cast<const bf16x8*>(
                        &wlds[((size_t)(kk * 4 + t) * 64 + lane) * 8]);
                #pragma unroll
                for (int m = 0; m < 4; ++m)
                    acc[m][t] = __builtin_amdgcn_mfma_f32_16x16x32_bf16(
                            aS[cur][m][h], b, acc[m][t], 0, 0, 0);
            }
        }
    }

    // C/D layout: col = lane&15, row = (lane>>4)*4 + r   [measured m89/m91]
    // plain stores (nt stores inflated WRITE_SIZE 49->66 MB in v3)
    #pragma unroll
    for (int m = 0; m < 4; ++m)
        #pragma unroll
        for (int t = 0; t < 4; ++t)
            #pragma unroll
            for (int r = 0; r < 4; ++r) {
                int row = cellbase + m * 16 + hi * 4 + r;
                out[(size_t)row * F + t * 16 + lo] = acc[m][t][r];
            }
}

// ---------------- correctness-only fallback (no workspace) ----------------
__global__ void naive_kernel(const float* __restrict__ x,
                             const int* __restrict__ adjc,
                             const float* __restrict__ W,
                             float* __restrict__ out) {
    int n = blockIdx.x;
    int o = threadIdx.x;  // 64 threads
    float acc = 0.f;
    for (int j = 0; j < NH; ++j) {
        int idx = adjc[(size_t)n * NH + j];
        for (int f = 0; f < F; ++f)
            acc += x[(size_t)idx * F + f] * W[(size_t)(j * F + f) * F + o];
    }
    out[(size_t)n * F + o] = acc;
}

extern "C" void kernel_launch(void* const* d_in, const int* in_sizes, int n_in,
                              void* d_out, int out_size, void* d_ws, size_t ws_size,
                              hipStream_t stream) {
    const float* x    = (const float*)d_in[0];
    const int*   adjc = (const int*)d_in[1];
    const float* W    = (const float*)d_in[2];
    float* out = (float*)d_out;

    const size_t need_x = (size_t)N_CELLS * F * sizeof(unsigned short);  // 25165824
    const size_t need_w = (size_t)K_TOT * F * sizeof(unsigned short);    // 73728

    if (ws_size >= need_x + need_w) {
        unsigned short* xb = (unsigned short*)d_ws;
        unsigned short* wb = (unsigned short*)((char*)d_ws + need_x);
        convert_x_kernel<<<(N_CELLS * F / 8) / 256, 256, 0, stream>>>(x, xb);
        convert_w_kernel<<<(K_STEPS * 4 * 64) / 256, 256, 0, stream>>>(W, wb);
        fused_gather_gemm_v4<true><<<N_CELLS / 256, 256, 0, stream>>>(
                x, xb, adjc, wb, out);
    } else if (ws_size >= need_w) {
        unsigned short* wb = (unsigned short*)d_ws;
        convert_w_kernel<<<(K_STEPS * 4 * 64) / 256, 256, 0, stream>>>(W, wb);
        fused_gather_gemm_v4<false><<<N_CELLS / 256, 256, 0, stream>>>(
                x, nullptr, adjc, wb, out);
    } else {
        naive_kernel<<<N_CELLS, F, 0, stream>>>(x, adjc, W, out);
    }
}